// Round 1
// baseline (537.218 us; speedup 1.0000x reference)
//
#include <hip/hip_runtime.h>

static constexpr int kN = 100000;
static constexpr int kE = 1600000;
static constexpr float kEps = 1e-5f;

static constexpr int kBSH = 9;                          // 512 nodes per bucket
static constexpr int kNB = (kN + 511) >> kBSH;          // 196 buckets
static constexpr int kBCAP = 12288;                     // staging cap per bucket
static constexpr int kCHUNK = 4096;                     // edges per bin_k block
static constexpr int kPad = 16;                         // degree padding quantum

// H' is stored channel-QUARTERED: 4 dense arrays of 32B rows (3.2MB each for
// fp8-128ch / bf16-64ch). Quarter q lives on XCD pair {2q,2q+1} (blockIdx&7
// round-robin heuristic) so the random gather working set fits one 4MB L2.
static constexpr size_t kQStride = (size_t)(kN + 1) * 32;  // bytes per quarter (incl dummy row)

typedef __attribute__((ext_vector_type(8))) short short8;   // 8 bf16 = 4 VGPRs
typedef __attribute__((ext_vector_type(4))) float float4v;  // MFMA acc
typedef __attribute__((ext_vector_type(2))) float float2v;
typedef __attribute__((ext_vector_type(4))) unsigned int uint4v;

static __device__ inline unsigned short f2bf(float f) {
  union { float f; unsigned int u; } v; v.f = f;
  unsigned int r = v.u + 0x7fffu + ((v.u >> 16) & 1u);  // RNE
  return (unsigned short)(r >> 16);
}
static __device__ inline float bf2f(unsigned int bits16) {
  union { unsigned int u; float f; } v; v.u = bits16 << 16; return v.f;
}
static __device__ inline unsigned int pack2bf(float lo, float hi) {
  return (unsigned int)f2bf(lo) | ((unsigned int)f2bf(hi) << 16);
}

// ---------------------------------------------------------------- binning (phase 1)
__global__ __launch_bounds__(512) void bin_k(const int* __restrict__ src,
                                             const int* __restrict__ dst,
                                             int* __restrict__ gcursor,
                                             int2* __restrict__ gstage) {
  __shared__ int s_cnt[256];
  __shared__ int s_scan[256];
  __shared__ int s_base[256];
  __shared__ int s_cur[256];
  __shared__ int s_gb[256];
  __shared__ int2 s_stage[kCHUNK];
  int tid = threadIdx.x;
  int e0 = blockIdx.x * kCHUNK;
  int n = kE - e0; if (n > kCHUNK) n = kCHUNK;
  if (tid < 256) s_cnt[tid] = 0;
  __syncthreads();
  for (int j = tid; j < n; j += 512) {
    atomicAdd(&s_cnt[dst[e0 + j] >> kBSH], 1);
  }
  __syncthreads();
  int v = 0;
  if (tid < 256) { v = s_cnt[tid]; s_scan[tid] = v; }
  __syncthreads();
  #pragma unroll
  for (int o = 1; o < 256; o <<= 1) {
    int t = (tid >= o && tid < 256) ? s_scan[tid - o] : 0;
    __syncthreads();
    if (tid < 256) s_scan[tid] += t;
    __syncthreads();
  }
  if (tid < 256) {
    int excl = s_scan[tid] - v;
    s_base[tid] = excl;
    s_cur[tid] = excl;
  }
  __syncthreads();
  if (tid < kNB && s_cnt[tid] > 0) s_gb[tid] = atomicAdd(&gcursor[tid], s_cnt[tid]);
  for (int j = tid; j < n; j += 512) {
    int s = src[e0 + j];
    int d = dst[e0 + j];
    int p = atomicAdd(&s_cur[d >> kBSH], 1);
    s_stage[p] = make_int2(s, d);
  }
  __syncthreads();
  for (int j = tid; j < n; j += 512) {
    int2 e = s_stage[j];
    int b = e.y >> kBSH;
    gstage[(size_t)b * kBCAP + s_gb[b] + (j - s_base[b])] = e;
  }
}

// ---------------------------------------------------------------- hist + alloc (fused)
__global__ __launch_bounds__(256) void alloc_hist_k(const int2* __restrict__ gstage,
                                                    const int* __restrict__ gcursor,
                                                    int* __restrict__ counter,
                                                    int* __restrict__ deg,
                                                    int* __restrict__ row_start,
                                                    float* __restrict__ dinv) {
  __shared__ int s_deg[1 << kBSH];
  __shared__ int s_scan[256];
  __shared__ int s_bcast;
  int b = blockIdx.x, tid = threadIdx.x;
  int n0 = b << kBSH;
  s_deg[tid] = 0;
  s_deg[tid + 256] = 0;
  __syncthreads();
  int cnt = gcursor[b];
  const int2* seg = gstage + (size_t)b * kBCAP;
  for (int j = tid; j < cnt; j += 256) {
    atomicAdd(&s_deg[seg[j].y - n0], 1);
  }
  __syncthreads();
  int i0 = 2 * tid, i1 = 2 * tid + 1;
  int d0 = s_deg[i0], d1 = s_deg[i1];
  int pd0 = (d0 + kPad - 1) & ~(kPad - 1);
  int pd1 = (d1 + kPad - 1) & ~(kPad - 1);
  int sum = pd0 + pd1;
  s_scan[tid] = sum;
  __syncthreads();
  #pragma unroll
  for (int o = 1; o < 256; o <<= 1) {
    int t = (tid >= o) ? s_scan[tid - o] : 0;
    __syncthreads();
    s_scan[tid] += t;
    __syncthreads();
  }
  if (tid == 255) s_bcast = atomicAdd(counter, s_scan[255]);
  __syncthreads();
  int base = s_bcast + s_scan[tid] - sum;
  int node0 = n0 + i0, node1 = n0 + i1;
  if (node0 < kN) {
    deg[node0] = d0;
    row_start[node0] = base;
    dinv[node0] = rsqrtf((float)(d0 + 1));
  }
  if (node1 < kN) {
    deg[node1] = d1;
    row_start[node1] = base + pd0;
    dinv[node1] = rsqrtf((float)(d1 + 1));
  }
}

// ---------------------------------------------------------------- scatter (phase 2)
__global__ __launch_bounds__(256) void scatter2_k(const int2* __restrict__ gstage,
                                                  const int* __restrict__ gcursor,
                                                  const int* __restrict__ rowst,
                                                  const int* __restrict__ deg,
                                                  int* __restrict__ csr_src) {
  __shared__ int s_cur[1 << kBSH];
  int b = blockIdx.x, tid = threadIdx.x;
  int n0 = b << kBSH;
  int nn = kN - n0; if (nn > (1 << kBSH)) nn = 1 << kBSH;
  for (int i = tid; i < nn; i += 256) s_cur[i] = rowst[n0 + i];
  __syncthreads();
  int cnt = gcursor[b];
  const int2* seg = gstage + (size_t)b * kBCAP;
  for (int j = tid; j < cnt; j += 256) {
    int2 e = seg[j];
    int pos = atomicAdd(&s_cur[e.y - n0], 1);
    csr_src[pos] = e.x;
  }
  __syncthreads();
  for (int i = tid; i < nn; i += 256) {
    int d = deg[n0 + i];
    int endp = rowst[n0 + i] + ((d + kPad - 1) & ~(kPad - 1));
    for (int p = s_cur[i]; p < endp; ++p) csr_src[p] = kN;
  }
}

// ---------------------------------------------------------------- weight convert + dummy-row zero
__global__ void convert_w_all_k(const float* __restrict__ W1, const float* __restrict__ W2,
                                const float* __restrict__ W3,
                                unsigned short* __restrict__ wf1,
                                unsigned short* __restrict__ wf2,
                                unsigned short* __restrict__ wf3,
                                unsigned char* __restrict__ hF8,
                                unsigned short* __restrict__ hH) {
  int tid = blockIdx.x * blockDim.x + threadIdx.x;
  const float* W;
  unsigned short* Wf;
  int BNO;
  if (tid < 2048) { W = W1; Wf = wf1; BNO = 128; }
  else if (tid < 4096) { W = W2; Wf = wf2; BNO = 128; tid -= 2048; }
  else if (tid < 5120) { W = W3; Wf = wf3; BNO = 64; tid -= 4096; }
  else if (tid < 5152) {  // zero dummy fp8 rows: 4 quarters x 32B (8 uints each)
    int k = tid - 5120;   // 0..31
    unsigned int* p = (unsigned int*)(hF8 + (size_t)(k >> 3) * kQStride + (size_t)kN * 32);
    p[k & 7] = 0u;
    return;
  } else if (tid < 5184) {  // zero dummy bf16 rows: 4 quarters x 32B
    int k = tid - 5152;
    unsigned int* p = (unsigned int*)((unsigned char*)hH + (size_t)(k >> 3) * kQStride + (size_t)kN * 32);
    p[k & 7] = 0u;
    return;
  } else return;
  int l = tid & 63;
  int frag = tid >> 6;
  int q = frag & 3;
  int t = frag >> 2;
  int n = t * 16 + (l & 15);
  int kbase = q * 32 + ((l >> 4) << 3);
  unsigned short v[8] __attribute__((aligned(16)));
  #pragma unroll
  for (int j = 0; j < 8; ++j) v[j] = f2bf(W[(kbase + j) * BNO + n]);
  ((uint4*)Wf)[tid] = *(const uint4*)v;
}

// ---------------------------------------------------------------- MFMA GEMM -> H' (quartered out)
template <int BNO, bool AF32, bool OUT8>
__global__ __launch_bounds__(256) void gemm_mfma_k(const void* __restrict__ Aptr,
                                                   const unsigned short* __restrict__ Wf,
                                                   const float* __restrict__ dinv,
                                                   void* __restrict__ Cptr,
                                                   float* __restrict__ stats) {
  if (stats && blockIdx.x == 0) stats[threadIdx.x] = 0.f;
  int wid = (int)((blockIdx.x * blockDim.x + threadIdx.x) >> 6);
  if (wid >= kN / 16) return;  // 100000 = 16 * 6250
  int l = threadIdx.x & 63;
  int r0 = wid * 16;
  short8 a[4];
  if constexpr (AF32) {
    const float* Af = (const float*)Aptr + (size_t)(r0 + (l & 15)) * 128 + ((l >> 4) << 3);
    #pragma unroll
    for (int q = 0; q < 4; ++q) {
      float4 u0 = *(const float4*)(Af + q * 32);
      float4 u1 = *(const float4*)(Af + q * 32 + 4);
      short8 t;
      t[0] = (short)f2bf(u0.x); t[1] = (short)f2bf(u0.y);
      t[2] = (short)f2bf(u0.z); t[3] = (short)f2bf(u0.w);
      t[4] = (short)f2bf(u1.x); t[5] = (short)f2bf(u1.y);
      t[6] = (short)f2bf(u1.z); t[7] = (short)f2bf(u1.w);
      a[q] = t;
    }
  } else {
    const short8* Arow =
        (const short8*)((const unsigned short*)Aptr + (size_t)(r0 + (l & 15)) * 128 + ((l >> 4) << 3));
    #pragma unroll
    for (int q = 0; q < 4; ++q) a[q] = Arow[q * 4];
  }
  const short8* Wv = (const short8*)Wf + l;
  constexpr int NT = BNO / 16;
  float4v acc[NT];
  #pragma unroll
  for (int t = 0; t < NT; ++t) {
    acc[t] = (float4v){0.f, 0.f, 0.f, 0.f};
    #pragma unroll
    for (int q = 0; q < 4; ++q) {
      short8 b = Wv[(t * 4 + q) * 64];
      acc[t] = __builtin_amdgcn_mfma_f32_16x16x32_bf16(a[q], b, acc[t], 0, 0, 0);
    }
  }
  int orow = r0 + ((l >> 4) << 2);
  int ocol = l & 15;
  float dv[4];
  #pragma unroll
  for (int r = 0; r < 4; ++r) dv[r] = dinv[orow + r];
  #pragma unroll
  for (int t = 0; t < NT; ++t) {
    #pragma unroll
    for (int r = 0; r < 4; ++r) {
      float val = acc[t][r] * dv[r];
      int c = t * 16 + ocol;
      if constexpr (OUT8) {
        unsigned int u = __builtin_amdgcn_cvt_pk_fp8_f32(val, val, 0u, false);
        unsigned char* p = (unsigned char*)Cptr + (size_t)(c >> 5) * kQStride;
        p[(size_t)(orow + r) * 32 + (c & 31)] = (unsigned char)(u & 0xffu);
      } else {
        unsigned short* p = (unsigned short*)((unsigned char*)Cptr + (size_t)(c >> 4) * kQStride);
        p[(size_t)(orow + r) * 16 + (c & 15)] = f2bf(val);
      }
    }
  }
}

// ---------------------------------------------------------------- aggregation (F=128, fp8 H', quartered)
// 4 nodes/wave, 16 lanes/node: ql=lane&3 (uint2 in 32B row), qt=(lane>>2)&3
// (edge slot), nsub=lane>>4 (node). Quarter q fixed per block via blockIdx&7
// -> XCD pair; streaming traffic (csr/meta/out) nontemporal to keep the
// 3.2MB quarter resident in the XCD's 4MB L2.
__global__ __launch_bounds__(256) void aggregate128_k(
    const unsigned char* __restrict__ H8, const int* __restrict__ row_start,
    const int* __restrict__ deg, const int* __restrict__ csr_src,
    const float* __restrict__ dinv, const float* __restrict__ bias,
    unsigned int* __restrict__ outp, float* __restrict__ stats) {
  __shared__ float s_sum[128], s_sq[128];
  int tid = threadIdx.x;
  if (tid < 128) { s_sum[tid] = 0.f; s_sq[tid] = 0.f; }
  __syncthreads();
  int lane = tid & 63;
  int ql = lane & 3;
  int qt = (lane >> 2) & 3;
  int nsub = lane >> 4;
  int xcd = blockIdx.x & 7;
  int q = xcd >> 1;
  int lb = ((blockIdx.x >> 3) << 1) | (xcd & 1);  // 0..511 within quarter-group
  int gw = lb * 4 + (tid >> 6);                   // group-wave 0..2047
  constexpr int GW = 2048;
  constexpr int NBATCH = kN / 4;                  // 25000 exact
  const uint2* H2 = (const uint2*)(H8 + (size_t)q * kQStride);
  float4 blo = ((const float4*)bias)[q * 8 + ql * 2];
  float4 bhi = ((const float4*)bias)[q * 8 + ql * 2 + 1];
  float st[8] = {0.f, 0.f, 0.f, 0.f, 0.f, 0.f, 0.f, 0.f};
  float sqa[8] = {0.f, 0.f, 0.f, 0.f, 0.f, 0.f, 0.f, 0.f};
  auto accum = [](float2v (&a)[4], uint2 v) {
    a[0] += __builtin_amdgcn_cvt_pk_f32_fp8(v.x, false);
    a[1] += __builtin_amdgcn_cvt_pk_f32_fp8(v.x, true);
    a[2] += __builtin_amdgcn_cvt_pk_f32_fp8(v.y, false);
    a[3] += __builtin_amdgcn_cvt_pk_f32_fp8(v.y, true);
  };
  int batch = gw;
  int node = 0, rs = 0, pd = 0, e0 = kN, e1 = kN;
  float di = 1.f;
  auto loadmeta = [&](int b, int& node_, int& rs_, int& pd_, float& di_, int& e0_, int& e1_) {
    node_ = b * 4 + nsub;
    rs_ = __builtin_nontemporal_load(row_start + node_);
    int dg = __builtin_nontemporal_load(deg + node_);
    pd_ = (dg + kPad - 1) & ~(kPad - 1);
    di_ = __builtin_nontemporal_load(dinv + node_);
    e0_ = __builtin_nontemporal_load(csr_src + rs_ + (lane & 15));
    e1_ = kN;
    if (pd_ > 16) e1_ = __builtin_nontemporal_load(csr_src + rs_ + 16 + (lane & 15));
  };
  if (batch < NBATCH) loadmeta(batch, node, rs, pd, di, e0, e1);
  while (batch < NBATCH) {
    int cn = node, crs = rs, cpd = pd, ce0 = e0, ce1 = e1;
    float cdi = di;
    int nb = batch + GW;
    if (nb < NBATCH) loadmeta(nb, node, rs, pd, di, e0, e1);
    uint2 vself = H2[(size_t)cn * 4 + ql];
    float2v a[4] = {{0.f, 0.f}, {0.f, 0.f}, {0.f, 0.f}, {0.f, 0.f}};
    int pm = cpd;
    { int t1 = __shfl_xor(pm, 16, 64); pm = pm < t1 ? t1 : pm;
      int t2 = __shfl_xor(pm, 32, 64); pm = pm < t2 ? t2 : pm; }
    int ng = pm >> 4;  // wave-uniform group count
    auto gather16 = [&](int eg, int g) {
      int s[4];
      #pragma unroll
      for (int i = 0; i < 4; ++i) {
        int se = __shfl(eg, (lane & 48) + i * 4 + qt, 64);
        s[i] = (g * 16 + i * 4 + qt < cpd) ? se : kN;  // dummy row = zeros
      }
      uint2 v[4];
      #pragma unroll
      for (int i = 0; i < 4; ++i) v[i] = H2[(size_t)s[i] * 4 + ql];
      #pragma unroll
      for (int i = 0; i < 4; ++i) accum(a, v[i]);
    };
    if (ng > 0) gather16(ce0, 0);
    if (ng > 1) gather16(ce1, 1);
    for (int g = 2; g < ng; ++g) {  // rare deg > 32
      int ee = kN;
      if (cpd > g * 16) ee = __builtin_nontemporal_load(csr_src + crs + g * 16 + (lane & 15));
      gather16(ee, g);
    }
    #pragma unroll
    for (int j = 0; j < 4; ++j) {  // reduce over 4 edge slots (xor4, xor8)
      float2v t;
      t.x = __shfl_xor(a[j].x, 4, 64); t.y = __shfl_xor(a[j].y, 4, 64);
      a[j] += t;
      t.x = __shfl_xor(a[j].x, 8, 64); t.y = __shfl_xor(a[j].y, 8, 64);
      a[j] += t;
    }
    accum(a, vself);  // self term, post-reduce (counted once)
    if (qt == 0) {
      float o[8];
      o[0] = cdi * a[0].x + blo.x; o[1] = cdi * a[0].y + blo.y;
      o[2] = cdi * a[1].x + blo.z; o[3] = cdi * a[1].y + blo.w;
      o[4] = cdi * a[2].x + bhi.x; o[5] = cdi * a[2].y + bhi.y;
      o[6] = cdi * a[3].x + bhi.z; o[7] = cdi * a[3].y + bhi.w;
      uint4v ov;
      ov[0] = pack2bf(o[0], o[1]); ov[1] = pack2bf(o[2], o[3]);
      ov[2] = pack2bf(o[4], o[5]); ov[3] = pack2bf(o[6], o[7]);
      __builtin_nontemporal_store(ov, (uint4v*)outp + (size_t)cn * 16 + q * 4 + ql);
      #pragma unroll
      for (int j = 0; j < 8; ++j) { st[j] += o[j]; sqa[j] += o[j] * o[j]; }
    }
    batch = nb;
  }
  if (qt == 0) {
    int c0 = q * 32 + ql * 8;
    #pragma unroll
    for (int j = 0; j < 8; ++j) {
      atomicAdd(&s_sum[c0 + j], st[j]);
      atomicAdd(&s_sq[c0 + j], sqa[j]);
    }
  }
  __syncthreads();
  if (tid < 128) {
    atomicAdd(&stats[tid], s_sum[tid]);
    atomicAdd(&stats[128 + tid], s_sq[tid]);
  }
}

// ---------------------------------------------------------------- aggregation (F=64, final, bf16, quartered)
__global__ __launch_bounds__(256) void aggregate64_k(
    const unsigned short* __restrict__ Hb, const int* __restrict__ row_start,
    const int* __restrict__ deg, const int* __restrict__ csr_src,
    const float* __restrict__ dinv, const float* __restrict__ bias,
    float* __restrict__ outp) {
  int tid = threadIdx.x;
  int lane = tid & 63;
  int ql = lane & 3;          // uint2 in 32B row-quarter (4 bf16 ch)
  int qt = (lane >> 2) & 3;
  int nsub = lane >> 4;
  int xcd = blockIdx.x & 7;
  int q = xcd >> 1;
  int lb = ((blockIdx.x >> 3) << 1) | (xcd & 1);
  int gw = lb * 4 + (tid >> 6);
  constexpr int GW = 2048;
  constexpr int NBATCH = kN / 4;
  const uint2* H2 = (const uint2*)((const unsigned char*)Hb + (size_t)q * kQStride);
  float4 b4 = ((const float4*)bias)[q * 4 + ql];
  auto accum = [](float2v (&a)[2], uint2 v) {
    union { unsigned int u; float f; } w0, w1, w2, w3;
    w0.u = v.x << 16; w1.u = v.x & 0xffff0000u;
    w2.u = v.y << 16; w3.u = v.y & 0xffff0000u;
    a[0].x += w0.f; a[0].y += w1.f;
    a[1].x += w2.f; a[1].y += w3.f;
  };
  int batch = gw;
  int node = 0, rs = 0, pd = 0, e0 = kN, e1 = kN;
  float di = 1.f;
  auto loadmeta = [&](int b, int& node_, int& rs_, int& pd_, float& di_, int& e0_, int& e1_) {
    node_ = b * 4 + nsub;
    rs_ = __builtin_nontemporal_load(row_start + node_);
    int dg = __builtin_nontemporal_load(deg + node_);
    pd_ = (dg + kPad - 1) & ~(kPad - 1);
    di_ = __builtin_nontemporal_load(dinv + node_);
    e0_ = __builtin_nontemporal_load(csr_src + rs_ + (lane & 15));
    e1_ = kN;
    if (pd_ > 16) e1_ = __builtin_nontemporal_load(csr_src + rs_ + 16 + (lane & 15));
  };
  if (batch < NBATCH) loadmeta(batch, node, rs, pd, di, e0, e1);
  while (batch < NBATCH) {
    int cn = node, crs = rs, cpd = pd, ce0 = e0, ce1 = e1;
    float cdi = di;
    int nb = batch + GW;
    if (nb < NBATCH) loadmeta(nb, node, rs, pd, di, e0, e1);
    uint2 vself = H2[(size_t)cn * 4 + ql];
    float2v a[2] = {{0.f, 0.f}, {0.f, 0.f}};
    int pm = cpd;
    { int t1 = __shfl_xor(pm, 16, 64); pm = pm < t1 ? t1 : pm;
      int t2 = __shfl_xor(pm, 32, 64); pm = pm < t2 ? t2 : pm; }
    int ng = pm >> 4;
    auto gather16 = [&](int eg, int g) {
      int s[4];
      #pragma unroll
      for (int i = 0; i < 4; ++i) {
        int se = __shfl(eg, (lane & 48) + i * 4 + qt, 64);
        s[i] = (g * 16 + i * 4 + qt < cpd) ? se : kN;
      }
      uint2 v[4];
      #pragma unroll
      for (int i = 0; i < 4; ++i) v[i] = H2[(size_t)s[i] * 4 + ql];
      #pragma unroll
      for (int i = 0; i < 4; ++i) accum(a, v[i]);
    };
    if (ng > 0) gather16(ce0, 0);
    if (ng > 1) gather16(ce1, 1);
    for (int g = 2; g < ng; ++g) {
      int ee = kN;
      if (cpd > g * 16) ee = __builtin_nontemporal_load(csr_src + crs + g * 16 + (lane & 15));
      gather16(ee, g);
    }
    #pragma unroll
    for (int j = 0; j < 2; ++j) {
      float2v t;
      t.x = __shfl_xor(a[j].x, 4, 64); t.y = __shfl_xor(a[j].y, 4, 64);
      a[j] += t;
      t.x = __shfl_xor(a[j].x, 8, 64); t.y = __shfl_xor(a[j].y, 8, 64);
      a[j] += t;
    }
    accum(a, vself);
    if (qt == 0) {
      float4v ov;
      ov[0] = cdi * a[0].x + b4.x; ov[1] = cdi * a[0].y + b4.y;
      ov[2] = cdi * a[1].x + b4.z; ov[3] = cdi * a[1].y + b4.w;
      __builtin_nontemporal_store(ov, (float4v*)outp + (size_t)cn * 16 + q * 4 + ql);
    }
    batch = nb;
  }
}

// ---------------------------------------------------------------- BN apply (finalize fused)
template <bool WRITE_Z, bool RF32>
__global__ void bn_apply_res_k(const unsigned int* __restrict__ a, const void* __restrict__ rp,
                               const float* __restrict__ stats, const float* __restrict__ g,
                               const float* __restrict__ be, unsigned int* __restrict__ z,
                               unsigned int* __restrict__ rb) {
  __shared__ float lss[256];
  int t = threadIdx.x;
  if (t < 128) {
    float mean = stats[t] * (1.f / kN);
    float var = stats[128 + t] * (1.f / kN) - mean * mean;
    float inv = rsqrtf(var + kEps);
    float sc = g[t] * inv;
    lss[t] = sc;
    lss[128 + t] = be[t] - mean * sc;
  }
  __syncthreads();
  int idx = blockIdx.x * blockDim.x + t;  // kN*16 groups of 8 bf16
  if (idx >= kN * 16) return;
  uint4 av = ((const uint4*)a)[idx];
  float r[8];
  if constexpr (RF32) {
    float4 r0 = ((const float4*)rp)[idx * 2];
    float4 r1 = ((const float4*)rp)[idx * 2 + 1];
    r[0] = r0.x; r[1] = r0.y; r[2] = r0.z; r[3] = r0.w;
    r[4] = r1.x; r[5] = r1.y; r[6] = r1.z; r[7] = r1.w;
  } else {
    uint4 rv = ((const uint4*)rp)[idx];
    r[0] = bf2f(rv.x & 0xffffu); r[1] = bf2f(rv.x >> 16);
    r[2] = bf2f(rv.y & 0xffffu); r[3] = bf2f(rv.y >> 16);
    r[4] = bf2f(rv.z & 0xffffu); r[5] = bf2f(rv.z >> 16);
    r[6] = bf2f(rv.w & 0xffffu); r[7] = bf2f(rv.w >> 16);
  }
  int c = (idx & 15) * 8;
  float o[8];
  unsigned int apk[4] = {av.x, av.y, av.z, av.w};
  #pragma unroll
  for (int j = 0; j < 4; ++j) {
    o[2 * j]     = lss[c + 2 * j] * bf2f(apk[j] & 0xffffu) + lss[128 + c + 2 * j] + r[2 * j];
    o[2 * j + 1] = lss[c + 2 * j + 1] * bf2f(apk[j] >> 16) + lss[128 + c + 2 * j + 1] + r[2 * j + 1];
  }
  if (WRITE_Z) {
    uint4 zv;
    zv.x = pack2bf(o[0], o[1]); zv.y = pack2bf(o[2], o[3]);
    zv.z = pack2bf(o[4], o[5]); zv.w = pack2bf(o[6], o[7]);
    ((uint4*)z)[idx] = zv;
  }
  uint4 hv;
  hv.x = pack2bf(fmaxf(o[0], 0.f), fmaxf(o[1], 0.f));
  hv.y = pack2bf(fmaxf(o[2], 0.f), fmaxf(o[3], 0.f));
  hv.z = pack2bf(fmaxf(o[4], 0.f), fmaxf(o[5], 0.f));
  hv.w = pack2bf(fmaxf(o[6], 0.f), fmaxf(o[7], 0.f));
  ((uint4*)rb)[idx] = hv;
}

// ---------------------------------------------------------------- launch
extern "C" void kernel_launch(void* const* d_in, const int* in_sizes, int n_in,
                              void* d_out, int out_size, void* d_ws, size_t ws_size,
                              hipStream_t stream) {
  const float* x   = (const float*)d_in[0];
  const int*   ei  = (const int*)d_in[1];
  const float* W1  = (const float*)d_in[2];
  const float* b1  = (const float*)d_in[3];
  const float* g1  = (const float*)d_in[4];
  const float* be1 = (const float*)d_in[5];
  const float* W2  = (const float*)d_in[6];
  const float* b2  = (const float*)d_in[7];
  const float* g2  = (const float*)d_in[8];
  const float* be2 = (const float*)d_in[9];
  const float* W3  = (const float*)d_in[10];
  const float* b3  = (const float*)d_in[11];
  float* outp = (float*)d_out;

  const int* src = ei;
  const int* dst = ei + kE;

  char* ws = (char*)d_ws;
  size_t off = 0;
  auto alloc = [&](size_t bytes) -> void* {
    void* p = ws + off;
    off = (off + bytes + 255) & ~size_t(255);
    return p;
  };
  // Quartered H' buffers: 4 x (kN+1) rows x 32B (dummy zero row at kN per quarter).
  unsigned char* hF8 = (unsigned char*)alloc(4 * kQStride);             // H' fp8 (layers 1-2)
  unsigned short* hH = (unsigned short*)alloc(4 * kQStride);            // H' bf16 (layer 3)
  unsigned int* aB = (unsigned int*)alloc((size_t)kN * 64 * 4);       // agg out (packed bf16)
  unsigned int* zC = (unsigned int*)alloc((size_t)kN * 64 * 4);       // z1 residual (packed bf16)
  unsigned int* hb = (unsigned int*)alloc((size_t)kN * 64 * 4);       // relu out / gemm in
  int*   csr_src  = (int*)alloc((size_t)(3200000 + 64) * 4);          // padded CSR + overread guard
  int2*  gstage   = (int2*)alloc((size_t)kNB * kBCAP * 8);            // ~19.3 MB
  int*   gcursor  = (int*)alloc((kNB + 1) * 4);
  int*   counter  = gcursor + kNB;
  int*   deg      = (int*)alloc((size_t)kN * 4);
  float* dinv     = (float*)alloc((size_t)kN * 4);
  int*   rowst    = (int*)alloc((size_t)kN * 4);
  float* stats    = (float*)alloc(256 * 4);
  unsigned short* wf1 = (unsigned short*)alloc(128 * 128 * 2);
  unsigned short* wf2 = (unsigned short*)alloc(128 * 128 * 2);
  unsigned short* wf3 = (unsigned short*)alloc(128 * 64 * 2);

  const int TB = 256;
  int blkBin = (kE + kCHUNK - 1) / kCHUNK;  // 391 (512 threads each)
  int blkGemm = (kN / 16 + 3) / 4;
  int blkApply = kN * 16 / TB;      // 6250
  const int blkAgg = 2048;          // must be %8==0: quarter q on XCDs {2q,2q+1}

  hipMemsetAsync(gcursor, 0, (kNB + 1) * 4, stream);
  bin_k<<<blkBin, 512, 0, stream>>>(src, dst, gcursor, gstage);
  alloc_hist_k<<<kNB, TB, 0, stream>>>(gstage, gcursor, counter, deg, rowst, dinv);
  scatter2_k<<<kNB, TB, 0, stream>>>(gstage, gcursor, rowst, deg, csr_src);
  convert_w_all_k<<<21, TB, 0, stream>>>(W1, W2, W3, wf1, wf2, wf3, hF8, hH);

  // Layer 1 (A = fp32 x, residual = fp32 x); H' in fp8 quarters
  gemm_mfma_k<128, true, true><<<blkGemm, 256, 0, stream>>>(x, wf1, dinv, hF8, stats);
  aggregate128_k<<<blkAgg, TB, 0, stream>>>(hF8, rowst, deg, csr_src, dinv, b1, aB, stats);
  bn_apply_res_k<true, true><<<blkApply, TB, 0, stream>>>(aB, x, stats, g1, be1, zC, hb);

  // Layer 2 (residual = z1 bf16); H' in fp8 quarters
  gemm_mfma_k<128, false, true><<<blkGemm, 256, 0, stream>>>((const unsigned short*)hb, wf2, dinv, hF8, stats);
  aggregate128_k<<<blkAgg, TB, 0, stream>>>(hF8, rowst, deg, csr_src, dinv, b2, aB, stats);
  bn_apply_res_k<false, false><<<blkApply, TB, 0, stream>>>(aB, zC, stats, g2, be2, nullptr, hb);

  // Layer 3: H' in bf16 quarters (final output path — keep precision)
  gemm_mfma_k<64, false, false><<<blkGemm, 256, 0, stream>>>((const unsigned short*)hb, wf3, dinv, hH, nullptr);
  aggregate64_k<<<blkAgg, TB, 0, stream>>>(hH, rowst, deg, csr_src, dinv, b3, outp);
}

// Round 2
// 435.707 us; speedup vs baseline: 1.2330x; 1.2330x over previous
//
#include <hip/hip_runtime.h>

static constexpr int kN = 100000;
static constexpr int kE = 1600000;
static constexpr float kEps = 1e-5f;

static constexpr int kBSH = 9;                          // 512 nodes per bucket
static constexpr int kNB = (kN + 511) >> kBSH;          // 196 buckets
static constexpr int kBCAP = 12288;                     // staging cap per bucket
static constexpr int kCHUNK = 4096;                     // edges per bin_k block
static constexpr int kPad = 16;                         // degree padding quantum

typedef __attribute__((ext_vector_type(8))) short short8;   // 8 bf16 = 4 VGPRs
typedef __attribute__((ext_vector_type(4))) float float4v;  // MFMA acc
typedef __attribute__((ext_vector_type(2))) float float2v;

static __device__ inline unsigned short f2bf(float f) {
  union { float f; unsigned int u; } v; v.f = f;
  unsigned int r = v.u + 0x7fffu + ((v.u >> 16) & 1u);  // RNE
  return (unsigned short)(r >> 16);
}
static __device__ inline float bf2f(unsigned int bits16) {
  union { unsigned int u; float f; } v; v.u = bits16 << 16; return v.f;
}
static __device__ inline unsigned int pack2bf(float lo, float hi) {
  return (unsigned int)f2bf(lo) | ((unsigned int)f2bf(hi) << 16);
}

// ---------------------------------------------------------------- binning (phase 1)
__global__ __launch_bounds__(512) void bin_k(const int* __restrict__ src,
                                             const int* __restrict__ dst,
                                             int* __restrict__ gcursor,
                                             int2* __restrict__ gstage) {
  __shared__ int s_cnt[256];
  __shared__ int s_scan[256];
  __shared__ int s_base[256];
  __shared__ int s_cur[256];
  __shared__ int s_gb[256];
  __shared__ int2 s_stage[kCHUNK];
  int tid = threadIdx.x;
  int e0 = blockIdx.x * kCHUNK;
  int n = kE - e0; if (n > kCHUNK) n = kCHUNK;
  if (tid < 256) s_cnt[tid] = 0;
  __syncthreads();
  for (int j = tid; j < n; j += 512) {
    atomicAdd(&s_cnt[dst[e0 + j] >> kBSH], 1);
  }
  __syncthreads();
  int v = 0;
  if (tid < 256) { v = s_cnt[tid]; s_scan[tid] = v; }
  __syncthreads();
  #pragma unroll
  for (int o = 1; o < 256; o <<= 1) {
    int t = (tid >= o && tid < 256) ? s_scan[tid - o] : 0;
    __syncthreads();
    if (tid < 256) s_scan[tid] += t;
    __syncthreads();
  }
  if (tid < 256) {
    int excl = s_scan[tid] - v;
    s_base[tid] = excl;
    s_cur[tid] = excl;
  }
  __syncthreads();
  if (tid < kNB && s_cnt[tid] > 0) s_gb[tid] = atomicAdd(&gcursor[tid], s_cnt[tid]);
  for (int j = tid; j < n; j += 512) {
    int s = src[e0 + j];
    int d = dst[e0 + j];
    int p = atomicAdd(&s_cur[d >> kBSH], 1);
    s_stage[p] = make_int2(s, d);
  }
  __syncthreads();
  for (int j = tid; j < n; j += 512) {
    int2 e = s_stage[j];
    int b = e.y >> kBSH;
    gstage[(size_t)b * kBCAP + s_gb[b] + (j - s_base[b])] = e;
  }
}

// ---------------------------------------------------------------- hist + alloc (fused)
__global__ __launch_bounds__(256) void alloc_hist_k(const int2* __restrict__ gstage,
                                                    const int* __restrict__ gcursor,
                                                    int* __restrict__ counter,
                                                    int* __restrict__ deg,
                                                    int* __restrict__ row_start,
                                                    float* __restrict__ dinv) {
  __shared__ int s_deg[1 << kBSH];
  __shared__ int s_scan[256];
  __shared__ int s_bcast;
  int b = blockIdx.x, tid = threadIdx.x;
  int n0 = b << kBSH;
  s_deg[tid] = 0;
  s_deg[tid + 256] = 0;
  __syncthreads();
  int cnt = gcursor[b];
  const int2* seg = gstage + (size_t)b * kBCAP;
  for (int j = tid; j < cnt; j += 256) {
    atomicAdd(&s_deg[seg[j].y - n0], 1);
  }
  __syncthreads();
  int i0 = 2 * tid, i1 = 2 * tid + 1;
  int d0 = s_deg[i0], d1 = s_deg[i1];
  int pd0 = (d0 + kPad - 1) & ~(kPad - 1);
  int pd1 = (d1 + kPad - 1) & ~(kPad - 1);
  int sum = pd0 + pd1;
  s_scan[tid] = sum;
  __syncthreads();
  #pragma unroll
  for (int o = 1; o < 256; o <<= 1) {
    int t = (tid >= o) ? s_scan[tid - o] : 0;
    __syncthreads();
    s_scan[tid] += t;
    __syncthreads();
  }
  if (tid == 255) s_bcast = atomicAdd(counter, s_scan[255]);
  __syncthreads();
  int base = s_bcast + s_scan[tid] - sum;
  int node0 = n0 + i0, node1 = n0 + i1;
  if (node0 < kN) {
    deg[node0] = d0;
    row_start[node0] = base;
    dinv[node0] = rsqrtf((float)(d0 + 1));
  }
  if (node1 < kN) {
    deg[node1] = d1;
    row_start[node1] = base + pd0;
    dinv[node1] = rsqrtf((float)(d1 + 1));
  }
}

// ---------------------------------------------------------------- scatter (phase 2)
__global__ __launch_bounds__(256) void scatter2_k(const int2* __restrict__ gstage,
                                                  const int* __restrict__ gcursor,
                                                  const int* __restrict__ rowst,
                                                  const int* __restrict__ deg,
                                                  int* __restrict__ csr_src) {
  __shared__ int s_cur[1 << kBSH];
  int b = blockIdx.x, tid = threadIdx.x;
  int n0 = b << kBSH;
  int nn = kN - n0; if (nn > (1 << kBSH)) nn = 1 << kBSH;
  for (int i = tid; i < nn; i += 256) s_cur[i] = rowst[n0 + i];
  __syncthreads();
  int cnt = gcursor[b];
  const int2* seg = gstage + (size_t)b * kBCAP;
  for (int j = tid; j < cnt; j += 256) {
    int2 e = seg[j];
    int pos = atomicAdd(&s_cur[e.y - n0], 1);
    csr_src[pos] = e.x;
  }
  __syncthreads();
  // pad: fill [rowst+deg, rowst+pdeg) with dummy index kN
  for (int i = tid; i < nn; i += 256) {
    int d = deg[n0 + i];
    int endp = rowst[n0 + i] + ((d + kPad - 1) & ~(kPad - 1));
    for (int p = s_cur[i]; p < endp; ++p) csr_src[p] = kN;
  }
}

// ---------------------------------------------------------------- weight convert + dummy-row zero
__global__ void convert_w_all_k(const float* __restrict__ W1, const float* __restrict__ W2,
                                const float* __restrict__ W3,
                                unsigned short* __restrict__ wf1,
                                unsigned short* __restrict__ wf2,
                                unsigned short* __restrict__ wf3,
                                unsigned char* __restrict__ hF8,
                                unsigned short* __restrict__ hH) {
  int tid = blockIdx.x * blockDim.x + threadIdx.x;
  const float* W;
  unsigned short* Wf;
  int BNO;
  if (tid < 2048) { W = W1; Wf = wf1; BNO = 128; }
  else if (tid < 4096) { W = W2; Wf = wf2; BNO = 128; tid -= 2048; }
  else if (tid < 5120) { W = W3; Wf = wf3; BNO = 64; tid -= 4096; }
  else if (tid < 5152) {  // zero dummy fp8 row (128B = 32 uints)
    ((unsigned int*)(hF8 + (size_t)kN * 128))[tid - 5120] = 0u;
    return;
  } else if (tid < 5184) {  // zero dummy bf16 row (128B = 32 uints)
    ((unsigned int*)(hH + (size_t)kN * 64))[tid - 5152] = 0u;
    return;
  } else return;
  int l = tid & 63;
  int frag = tid >> 6;
  int q = frag & 3;
  int t = frag >> 2;
  int n = t * 16 + (l & 15);
  int kbase = q * 32 + ((l >> 4) << 3);
  unsigned short v[8] __attribute__((aligned(16)));
  #pragma unroll
  for (int j = 0; j < 8; ++j) v[j] = f2bf(W[(kbase + j) * BNO + n]);
  ((uint4*)Wf)[tid] = *(const uint4*)v;
}

// ---------------------------------------------------------------- MFMA GEMM -> H' out
template <int BNO, bool AF32, bool OUT8>
__global__ __launch_bounds__(256) void gemm_mfma_k(const void* __restrict__ Aptr,
                                                   const unsigned short* __restrict__ Wf,
                                                   const float* __restrict__ dinv,
                                                   void* __restrict__ Cptr,
                                                   float* __restrict__ stats) {
  if (stats && blockIdx.x == 0) stats[threadIdx.x] = 0.f;
  int wid = (int)((blockIdx.x * blockDim.x + threadIdx.x) >> 6);
  if (wid >= kN / 16) return;  // 100000 = 16 * 6250
  int l = threadIdx.x & 63;
  int r0 = wid * 16;
  short8 a[4];
  if constexpr (AF32) {
    const float* Af = (const float*)Aptr + (size_t)(r0 + (l & 15)) * 128 + ((l >> 4) << 3);
    #pragma unroll
    for (int q = 0; q < 4; ++q) {
      float4 u0 = *(const float4*)(Af + q * 32);
      float4 u1 = *(const float4*)(Af + q * 32 + 4);
      short8 t;
      t[0] = (short)f2bf(u0.x); t[1] = (short)f2bf(u0.y);
      t[2] = (short)f2bf(u0.z); t[3] = (short)f2bf(u0.w);
      t[4] = (short)f2bf(u1.x); t[5] = (short)f2bf(u1.y);
      t[6] = (short)f2bf(u1.z); t[7] = (short)f2bf(u1.w);
      a[q] = t;
    }
  } else {
    const short8* Arow =
        (const short8*)((const unsigned short*)Aptr + (size_t)(r0 + (l & 15)) * 128 + ((l >> 4) << 3));
    #pragma unroll
    for (int q = 0; q < 4; ++q) a[q] = Arow[q * 4];
  }
  const short8* Wv = (const short8*)Wf + l;
  constexpr int NT = BNO / 16;
  float4v acc[NT];
  #pragma unroll
  for (int t = 0; t < NT; ++t) {
    acc[t] = (float4v){0.f, 0.f, 0.f, 0.f};
    #pragma unroll
    for (int q = 0; q < 4; ++q) {
      short8 b = Wv[(t * 4 + q) * 64];
      acc[t] = __builtin_amdgcn_mfma_f32_16x16x32_bf16(a[q], b, acc[t], 0, 0, 0);
    }
  }
  int orow = r0 + ((l >> 4) << 2);
  int ocol = l & 15;
  float dv[4];
  #pragma unroll
  for (int r = 0; r < 4; ++r) dv[r] = dinv[orow + r];
  #pragma unroll
  for (int t = 0; t < NT; ++t) {
    #pragma unroll
    for (int r = 0; r < 4; ++r) {
      float val = acc[t][r] * dv[r];
      if constexpr (OUT8) {
        unsigned int u = __builtin_amdgcn_cvt_pk_fp8_f32(val, val, 0u, false);
        ((unsigned char*)Cptr)[(size_t)(orow + r) * BNO + t * 16 + ocol] = (unsigned char)(u & 0xffu);
      } else {
        ((unsigned short*)Cptr)[(size_t)(orow + r) * BNO + t * 16 + ocol] = f2bf(val);
      }
    }
  }
}

// ---------------------------------------------------------------- aggregation (F=128, fp8 H')
// Batch of 4 nodes per wave iteration. All gathers for the batch (4 nodes x
// {self, group0 x4, group1 x4 masked}) are issued before any accumulation:
// ~36 outstanding 8B loads/lane instead of ~4 -> hides gather latency.
// Group-1 loads masked to the zero dummy row (kN, L1-resident) when pd<32.
__global__ __launch_bounds__(256) void aggregate128_k(
    const unsigned char* __restrict__ H8, const int* __restrict__ row_start,
    const int* __restrict__ deg, const int* __restrict__ csr_src,
    const float* __restrict__ dinv, const float* __restrict__ bias,
    unsigned int* __restrict__ outp, float* __restrict__ stats) {
  __shared__ float s_sum[128], s_sq[128];
  int tid = threadIdx.x;
  if (tid < 128) { s_sum[tid] = 0.f; s_sq[tid] = 0.f; }
  __syncthreads();
  int lane = tid & 63;
  int qt = lane >> 4;    // edge slot within a quad of 4 edges
  int ql = lane & 15;    // uint2 index in row (channels 8ql..8ql+7)
  int nwaves = gridDim.x * (blockDim.x >> 6);
  int gwave = (int)((blockIdx.x * blockDim.x + tid) >> 6);
  const uint2* H2 = (const uint2*)H8;  // 16 uint2 per row
  float4 blo = ((const float4*)bias)[2 * ql];
  float4 bhi = ((const float4*)bias)[2 * ql + 1];
  float st[8] = {0.f, 0.f, 0.f, 0.f, 0.f, 0.f, 0.f, 0.f};
  float sqa[8] = {0.f, 0.f, 0.f, 0.f, 0.f, 0.f, 0.f, 0.f};
  auto accum = [](float (&a)[8], uint2 v) {
    float2v p0 = __builtin_amdgcn_cvt_pk_f32_fp8(v.x, false);
    float2v p1 = __builtin_amdgcn_cvt_pk_f32_fp8(v.x, true);
    float2v p2 = __builtin_amdgcn_cvt_pk_f32_fp8(v.y, false);
    float2v p3 = __builtin_amdgcn_cvt_pk_f32_fp8(v.y, true);
    a[0] += p0.x; a[1] += p0.y; a[2] += p1.x; a[3] += p1.y;
    a[4] += p2.x; a[5] += p2.y; a[6] += p3.x; a[7] += p3.y;
  };
  constexpr int NBATCH = kN / 4;  // 25000 exact
  int prs[4], ppd[4], pe[4];
  float pdi[4];
  auto loadbatch = [&](int b) {
    #pragma unroll
    for (int j = 0; j < 4; ++j) {
      int nd = b * 4 + j;
      prs[j] = row_start[nd];
      int dg = deg[nd];
      ppd[j] = (dg + kPad - 1) & ~(kPad - 1);
      pdi[j] = dinv[nd];
      pe[j] = csr_src[prs[j] + lane];  // 64 coalesced slots (covers deg<=64)
    }
  };
  int batch = gwave;
  if (batch < NBATCH) loadbatch(batch);
  while (batch < NBATCH) {
    int crs[4], cpd[4], ce[4];
    float cdi[4];
    #pragma unroll
    for (int j = 0; j < 4; ++j) {
      crs[j] = prs[j]; cpd[j] = ppd[j]; cdi[j] = pdi[j]; ce[j] = pe[j];
    }
    int nxt = batch + nwaves;
    if (nxt < NBATCH) loadbatch(nxt);  // prefetch next batch meta+csr
    // ---- stage 1: issue ALL gathers for this batch
    uint2 vs[4], g0[4][4], g1[4][4];
    #pragma unroll
    for (int j = 0; j < 4; ++j) {
      vs[j] = H2[(size_t)(batch * 4 + j) * 16 + ql];
      #pragma unroll
      for (int i = 0; i < 4; ++i) {
        int s0 = __shfl(ce[j], 4 * i + qt, 64);
        s0 = (cpd[j] > 0) ? s0 : kN;
        g0[j][i] = H2[(size_t)s0 * 16 + ql];
      }
      #pragma unroll
      for (int i = 0; i < 4; ++i) {
        int s1 = __shfl(ce[j], 16 + 4 * i + qt, 64);
        s1 = (cpd[j] >= 32) ? s1 : kN;  // dummy zero row when no group 1
        g1[j][i] = H2[(size_t)s1 * 16 + ql];
      }
    }
    // ---- stage 2: per-node accumulate / reduce / write
    #pragma unroll
    for (int j = 0; j < 4; ++j) {
      int cn = batch * 4 + j;
      float a[8] = {0.f, 0.f, 0.f, 0.f, 0.f, 0.f, 0.f, 0.f};
      #pragma unroll
      for (int i = 0; i < 4; ++i) accum(a, g0[j][i]);
      #pragma unroll
      for (int i = 0; i < 4; ++i) accum(a, g1[j][i]);
      int nb = cpd[j] >> 4;
      int nb4 = nb < 4 ? nb : 4;
      for (int g = 2; g < nb4; ++g) {  // deg in (32,64]
        int s[4];
        uint2 v[4];
        #pragma unroll
        for (int i = 0; i < 4; ++i) s[i] = __shfl(ce[j], g * 16 + 4 * i + qt, 64);
        #pragma unroll
        for (int i = 0; i < 4; ++i) v[i] = H2[(size_t)s[i] * 16 + ql];
        #pragma unroll
        for (int i = 0; i < 4; ++i) accum(a, v[i]);
      }
      for (int g = 4; g < nb; ++g) {  // rare deg > 64
        int ee = csr_src[crs[j] + g * 16 + (lane & 15)];
        int s[4];
        uint2 v[4];
        #pragma unroll
        for (int i = 0; i < 4; ++i) s[i] = __shfl(ee, 4 * i + qt, 64);
        #pragma unroll
        for (int i = 0; i < 4; ++i) v[i] = H2[(size_t)s[i] * 16 + ql];
        #pragma unroll
        for (int i = 0; i < 4; ++i) accum(a, v[i]);
      }
      #pragma unroll
      for (int k = 0; k < 8; ++k) {
        a[k] += __shfl_xor(a[k], 16, 64);
        a[k] += __shfl_xor(a[k], 32, 64);
      }
      accum(a, vs[j]);  // self term, post-reduce (counted once)
      if (qt == 0) {
        float o[8];
        o[0] = cdi[j] * a[0] + blo.x; o[1] = cdi[j] * a[1] + blo.y;
        o[2] = cdi[j] * a[2] + blo.z; o[3] = cdi[j] * a[3] + blo.w;
        o[4] = cdi[j] * a[4] + bhi.x; o[5] = cdi[j] * a[5] + bhi.y;
        o[6] = cdi[j] * a[6] + bhi.z; o[7] = cdi[j] * a[7] + bhi.w;
        uint4 ov;
        ov.x = pack2bf(o[0], o[1]); ov.y = pack2bf(o[2], o[3]);
        ov.z = pack2bf(o[4], o[5]); ov.w = pack2bf(o[6], o[7]);
        ((uint4*)outp)[(size_t)cn * 16 + ql] = ov;
        #pragma unroll
        for (int k = 0; k < 8; ++k) { st[k] += o[k]; sqa[k] += o[k] * o[k]; }
      }
    }
    batch = nxt;
  }
  if (qt == 0) {
    #pragma unroll
    for (int j = 0; j < 8; ++j) {
      atomicAdd(&s_sum[8 * ql + j], st[j]);
      atomicAdd(&s_sq[8 * ql + j], sqa[j]);
    }
  }
  __syncthreads();
  if (tid < 128) {
    atomicAdd(&stats[tid], s_sum[tid]);
    atomicAdd(&stats[128 + tid], s_sq[tid]);
  }
}

// ---------------------------------------------------------------- aggregation (F=64, final, bf16)
__global__ __launch_bounds__(256) void aggregate64_k(
    const unsigned short* __restrict__ Hb, const int* __restrict__ row_start,
    const int* __restrict__ deg, const int* __restrict__ csr_src,
    const float* __restrict__ dinv, const float* __restrict__ bias,
    float* __restrict__ outp) {
  int tid = threadIdx.x;
  int lane = tid & 63;
  int qt = lane >> 4;
  int ql = lane & 15;
  int nwaves = gridDim.x * (blockDim.x >> 6);
  int gwave = (int)((blockIdx.x * blockDim.x + tid) >> 6);
  const uint2* H2 = (const uint2*)Hb;  // 16 uint2 per row (cols 4ql..4ql+3)
  float4 b4 = ((const float4*)bias)[ql];
  auto accum = [](float (&a)[4], uint2 v) {
    a[0] += bf2f(v.x & 0xffffu); a[1] += bf2f(v.x >> 16);
    a[2] += bf2f(v.y & 0xffffu); a[3] += bf2f(v.y >> 16);
  };
  constexpr int NBATCH = kN / 4;
  int prs[4], ppd[4], pe[4];
  float pdi[4];
  auto loadbatch = [&](int b) {
    #pragma unroll
    for (int j = 0; j < 4; ++j) {
      int nd = b * 4 + j;
      prs[j] = row_start[nd];
      int dg = deg[nd];
      ppd[j] = (dg + kPad - 1) & ~(kPad - 1);
      pdi[j] = dinv[nd];
      pe[j] = csr_src[prs[j] + lane];
    }
  };
  int batch = gwave;
  if (batch < NBATCH) loadbatch(batch);
  while (batch < NBATCH) {
    int crs[4], cpd[4], ce[4];
    float cdi[4];
    #pragma unroll
    for (int j = 0; j < 4; ++j) {
      crs[j] = prs[j]; cpd[j] = ppd[j]; cdi[j] = pdi[j]; ce[j] = pe[j];
    }
    int nxt = batch + nwaves;
    if (nxt < NBATCH) loadbatch(nxt);
    uint2 vs[4], g0[4][4], g1[4][4];
    #pragma unroll
    for (int j = 0; j < 4; ++j) {
      vs[j] = H2[(size_t)(batch * 4 + j) * 16 + ql];
      #pragma unroll
      for (int i = 0; i < 4; ++i) {
        int s0 = __shfl(ce[j], 4 * i + qt, 64);
        s0 = (cpd[j] > 0) ? s0 : kN;
        g0[j][i] = H2[(size_t)s0 * 16 + ql];
      }
      #pragma unroll
      for (int i = 0; i < 4; ++i) {
        int s1 = __shfl(ce[j], 16 + 4 * i + qt, 64);
        s1 = (cpd[j] >= 32) ? s1 : kN;
        g1[j][i] = H2[(size_t)s1 * 16 + ql];
      }
    }
    #pragma unroll
    for (int j = 0; j < 4; ++j) {
      int cn = batch * 4 + j;
      float a[4] = {0.f, 0.f, 0.f, 0.f};
      #pragma unroll
      for (int i = 0; i < 4; ++i) accum(a, g0[j][i]);
      #pragma unroll
      for (int i = 0; i < 4; ++i) accum(a, g1[j][i]);
      int nb = cpd[j] >> 4;
      int nb4 = nb < 4 ? nb : 4;
      for (int g = 2; g < nb4; ++g) {
        int s[4];
        uint2 v[4];
        #pragma unroll
        for (int i = 0; i < 4; ++i) s[i] = __shfl(ce[j], g * 16 + 4 * i + qt, 64);
        #pragma unroll
        for (int i = 0; i < 4; ++i) v[i] = H2[(size_t)s[i] * 16 + ql];
        #pragma unroll
        for (int i = 0; i < 4; ++i) accum(a, v[i]);
      }
      for (int g = 4; g < nb; ++g) {
        int ee = csr_src[crs[j] + g * 16 + (lane & 15)];
        int s[4];
        uint2 v[4];
        #pragma unroll
        for (int i = 0; i < 4; ++i) s[i] = __shfl(ee, 4 * i + qt, 64);
        #pragma unroll
        for (int i = 0; i < 4; ++i) v[i] = H2[(size_t)s[i] * 16 + ql];
        #pragma unroll
        for (int i = 0; i < 4; ++i) accum(a, v[i]);
      }
      #pragma unroll
      for (int k = 0; k < 4; ++k) {
        a[k] += __shfl_xor(a[k], 16, 64);
        a[k] += __shfl_xor(a[k], 32, 64);
      }
      accum(a, vs[j]);
      if (qt == 0) {
        ((float4*)outp)[(size_t)cn * 16 + ql] =
            make_float4(cdi[j] * a[0] + b4.x, cdi[j] * a[1] + b4.y,
                        cdi[j] * a[2] + b4.z, cdi[j] * a[3] + b4.w);
      }
    }
    batch = nxt;
  }
}

// ---------------------------------------------------------------- BN apply (finalize fused)
template <bool WRITE_Z, bool RF32>
__global__ void bn_apply_res_k(const unsigned int* __restrict__ a, const void* __restrict__ rp,
                               const float* __restrict__ stats, const float* __restrict__ g,
                               const float* __restrict__ be, unsigned int* __restrict__ z,
                               unsigned int* __restrict__ rb) {
  __shared__ float lss[256];
  int t = threadIdx.x;
  if (t < 128) {
    float mean = stats[t] * (1.f / kN);
    float var = stats[128 + t] * (1.f / kN) - mean * mean;
    float inv = rsqrtf(var + kEps);
    float sc = g[t] * inv;
    lss[t] = sc;
    lss[128 + t] = be[t] - mean * sc;
  }
  __syncthreads();
  int idx = blockIdx.x * blockDim.x + t;  // kN*16 groups of 8 bf16
  if (idx >= kN * 16) return;
  uint4 av = ((const uint4*)a)[idx];
  float r[8];
  if constexpr (RF32) {
    float4 r0 = ((const float4*)rp)[idx * 2];
    float4 r1 = ((const float4*)rp)[idx * 2 + 1];
    r[0] = r0.x; r[1] = r0.y; r[2] = r0.z; r[3] = r0.w;
    r[4] = r1.x; r[5] = r1.y; r[6] = r1.z; r[7] = r1.w;
  } else {
    uint4 rv = ((const uint4*)rp)[idx];
    r[0] = bf2f(rv.x & 0xffffu); r[1] = bf2f(rv.x >> 16);
    r[2] = bf2f(rv.y & 0xffffu); r[3] = bf2f(rv.y >> 16);
    r[4] = bf2f(rv.z & 0xffffu); r[5] = bf2f(rv.z >> 16);
    r[6] = bf2f(rv.w & 0xffffu); r[7] = bf2f(rv.w >> 16);
  }
  int c = (idx & 15) * 8;
  float o[8];
  unsigned int apk[4] = {av.x, av.y, av.z, av.w};
  #pragma unroll
  for (int j = 0; j < 4; ++j) {
    o[2 * j]     = lss[c + 2 * j] * bf2f(apk[j] & 0xffffu) + lss[128 + c + 2 * j] + r[2 * j];
    o[2 * j + 1] = lss[c + 2 * j + 1] * bf2f(apk[j] >> 16) + lss[128 + c + 2 * j + 1] + r[2 * j + 1];
  }
  if (WRITE_Z) {
    uint4 zv;
    zv.x = pack2bf(o[0], o[1]); zv.y = pack2bf(o[2], o[3]);
    zv.z = pack2bf(o[4], o[5]); zv.w = pack2bf(o[6], o[7]);
    ((uint4*)z)[idx] = zv;
  }
  uint4 hv;
  hv.x = pack2bf(fmaxf(o[0], 0.f), fmaxf(o[1], 0.f));
  hv.y = pack2bf(fmaxf(o[2], 0.f), fmaxf(o[3], 0.f));
  hv.z = pack2bf(fmaxf(o[4], 0.f), fmaxf(o[5], 0.f));
  hv.w = pack2bf(fmaxf(o[6], 0.f), fmaxf(o[7], 0.f));
  ((uint4*)rb)[idx] = hv;
}

// ---------------------------------------------------------------- launch
extern "C" void kernel_launch(void* const* d_in, const int* in_sizes, int n_in,
                              void* d_out, int out_size, void* d_ws, size_t ws_size,
                              hipStream_t stream) {
  const float* x   = (const float*)d_in[0];
  const int*   ei  = (const int*)d_in[1];
  const float* W1  = (const float*)d_in[2];
  const float* b1  = (const float*)d_in[3];
  const float* g1  = (const float*)d_in[4];
  const float* be1 = (const float*)d_in[5];
  const float* W2  = (const float*)d_in[6];
  const float* b2  = (const float*)d_in[7];
  const float* g2  = (const float*)d_in[8];
  const float* be2 = (const float*)d_in[9];
  const float* W3  = (const float*)d_in[10];
  const float* b3  = (const float*)d_in[11];
  float* outp = (float*)d_out;

  const int* src = ei;
  const int* dst = ei + kE;

  char* ws = (char*)d_ws;
  size_t off = 0;
  auto alloc = [&](size_t bytes) -> void* {
    void* p = ws + off;
    off = (off + bytes + 255) & ~size_t(255);
    return p;
  };
  // +1 row on H' buffers: dummy zero row at index kN for degree padding.
  unsigned char* hF8 = (unsigned char*)alloc((size_t)(kN + 1) * 128);      // H' fp8 (layers 1-2)
  unsigned short* hH = (unsigned short*)alloc((size_t)(kN + 1) * 64 * 2);  // H' bf16 (layer 3)
  unsigned int* aB = (unsigned int*)alloc((size_t)kN * 64 * 4);       // agg out (packed bf16)
  unsigned int* zC = (unsigned int*)alloc((size_t)kN * 64 * 4);       // z1 residual (packed bf16)
  unsigned int* hb = (unsigned int*)alloc((size_t)kN * 64 * 4);       // relu out / gemm in
  int*   csr_src  = (int*)alloc((size_t)(3200000 + 64) * 4);          // padded CSR + overread guard
  int2*  gstage   = (int2*)alloc((size_t)kNB * kBCAP * 8);            // ~19.3 MB
  int*   gcursor  = (int*)alloc((kNB + 1) * 4);
  int*   counter  = gcursor + kNB;
  int*   deg      = (int*)alloc((size_t)kN * 4);
  float* dinv     = (float*)alloc((size_t)kN * 4);
  int*   rowst    = (int*)alloc((size_t)kN * 4);
  float* stats    = (float*)alloc(256 * 4);
  unsigned short* wf1 = (unsigned short*)alloc(128 * 128 * 2);
  unsigned short* wf2 = (unsigned short*)alloc(128 * 128 * 2);
  unsigned short* wf3 = (unsigned short*)alloc(128 * 64 * 2);

  const int TB = 256;
  int blkBin = (kE + kCHUNK - 1) / kCHUNK;  // 391 (512 threads each)
  int blkGemm = (kN / 16 + 3) / 4;
  int blkApply = kN * 16 / TB;      // 6250
  const int blkAgg = 1568;          // 6272 waves; 25000 batches -> ~4/wave, near-uniform

  hipMemsetAsync(gcursor, 0, (kNB + 1) * 4, stream);
  bin_k<<<blkBin, 512, 0, stream>>>(src, dst, gcursor, gstage);
  alloc_hist_k<<<kNB, TB, 0, stream>>>(gstage, gcursor, counter, deg, rowst, dinv);
  scatter2_k<<<kNB, TB, 0, stream>>>(gstage, gcursor, rowst, deg, csr_src);
  convert_w_all_k<<<21, TB, 0, stream>>>(W1, W2, W3, wf1, wf2, wf3, hF8, hH);

  // Layer 1 (A = fp32 x, residual = fp32 x); H' in fp8
  gemm_mfma_k<128, true, true><<<blkGemm, 256, 0, stream>>>(x, wf1, dinv, hF8, stats);
  aggregate128_k<<<blkAgg, TB, 0, stream>>>(hF8, rowst, deg, csr_src, dinv, b1, aB, stats);
  bn_apply_res_k<true, true><<<blkApply, TB, 0, stream>>>(aB, x, stats, g1, be1, zC, hb);

  // Layer 2 (residual = z1 bf16); H' in fp8
  gemm_mfma_k<128, false, true><<<blkGemm, 256, 0, stream>>>((const unsigned short*)hb, wf2, dinv, hF8, stats);
  aggregate128_k<<<blkAgg, TB, 0, stream>>>(hF8, rowst, deg, csr_src, dinv, b2, aB, stats);
  bn_apply_res_k<false, false><<<blkApply, TB, 0, stream>>>(aB, zC, stats, g2, be2, nullptr, hb);

  // Layer 3: H' in bf16 (final output path — keep precision)
  gemm_mfma_k<64, false, false><<<blkGemm, 256, 0, stream>>>((const unsigned short*)hb, wf3, dinv, hH, nullptr);
  aggregate64_k<<<blkAgg, TB, 0, stream>>>(hH, rowst, deg, csr_src, dinv, b3, outp);
}